// Round 14
// baseline (259.153 us; speedup 1.0000x reference)
//
#include <hip/hip_runtime.h>
#include <hip/hip_bf16.h>
#include <hip/hip_fp16.h>
#include <math.h>

// Problem constants
#define BB 2
#define TT 2048
#define DD 1024
#define HH 16
#define DK 64
#define KT 64             // keys per attention tile

typedef _Float16 f16x8 __attribute__((ext_vector_type(8)));
typedef __fp16 fp16x2 __attribute__((ext_vector_type(2)));
typedef __attribute__((ext_vector_type(4))) float f32x4;
typedef __attribute__((ext_vector_type(2))) float f32x2;

// async 16B global->LDS (lane i writes ldsbase + i*16)
static __device__ __forceinline__ void g2lds16(const void* g, void* l) {
    __builtin_amdgcn_global_load_lds(
        (const __attribute__((address_space(1))) unsigned int*)g,
        (__attribute__((address_space(3))) unsigned int*)l, 16, 0, 0);
}

// w = (1 - acos(clip(s,±0.999))/pi)^8 for a pair; rs accumulates pair sums.
// acos/pi via A&S 4.4.45 deg-3 (|err|<=5e-5 rad); reference's max(.,1e-6)
// is dead (clamp => t >= 0.0142). float2 ops lower to v_pk_* on gfx950.
// __builtin_amdgcn_sqrtf = raw v_sqrt_f32 (~1ulp, om in [1e-3,2] safe) —
// avoids the IEEE fixup sequence libm sqrtf emits (R7: -34% attn time).
static __device__ __forceinline__ f32x2 w8pair(f32x2 s, f32x2& rs) {
    f32x2 ax;
    ax.x = fminf(fabsf(s.x), 0.999f);
    ax.y = fminf(fabsf(s.y), 0.999f);
    f32x2 p = ax * -0.0059617f + 0.0236380f;
    p = p * ax + (-0.0675180f);
    p = p * ax + 0.49997851f;
    f32x2 om = 1.0f - ax;
    f32x2 u;
    u.x = __builtin_amdgcn_sqrtf(om.x);
    u.y = __builtin_amdgcn_sqrtf(om.y);
    f32x2 uq = u * p;
    f32x2 e = 0.5f - uq;
    f32x2 t;
    t.x = 0.5f + copysignf(e.x, s.x);
    t.y = 0.5f + copysignf(e.y, s.y);
    f32x2 t2 = t * t;
    f32x2 t4 = t2 * t2;
    f32x2 t8 = t4 * t4;
    rs += t8;
    return t8;
}
// one-instruction f16 pair pack (RTZ; |err|<=2^-11 rel, fine for W)
static __device__ __forceinline__ int packh2(f32x2 v) {
    union { fp16x2 h; int i; } u;
    u.h = __builtin_amdgcn_cvt_pkrtz(v.x, v.y);
    return u.i;
}

// ---------------------------------------------------------------------------
// One-launch fp32 -> f16 convert for x + all 4 weight matrices.
// bid < 2048: x -> xh. Wq/Wk/Wv -> W3h rows (contiguous). Wo -> Woh.
// ---------------------------------------------------------------------------
__global__ __launch_bounds__(256) void cvtall_kernel(
    const float* __restrict__ x,  const float* __restrict__ Wq,
    const float* __restrict__ Wk, const float* __restrict__ Wv,
    const float* __restrict__ Wo,
    _Float16* __restrict__ xh, _Float16* __restrict__ W3h,
    _Float16* __restrict__ Woh)
{
    const int bid = blockIdx.x;
    const float* s; _Float16* d; int blk;
    if (bid < 2048) { s = x; d = xh; blk = bid; }
    else {
        const int idx = bid - 2048;
        const int w   = idx >> 9;          // 0..3
        blk = idx & 511;
        s = (w == 0) ? Wq : (w == 1) ? Wk : (w == 2) ? Wv : Wo;
        d = (w == 3) ? Woh : W3h + (size_t)w * (DD * DD);
    }
    const int i = (blk * 256 + threadIdx.x) * 8;
    float4 a = *(const float4*)(s + i);
    float4 b = *(const float4*)(s + i + 4);
    union { _Float16 h[8]; int4 v; } u;
    u.h[0] = (_Float16)a.x; u.h[1] = (_Float16)a.y;
    u.h[2] = (_Float16)a.z; u.h[3] = (_Float16)a.w;
    u.h[4] = (_Float16)b.x; u.h[5] = (_Float16)b.y;
    u.h[6] = (_Float16)b.z; u.h[7] = (_Float16)b.w;
    *(int4*)(d + i) = u.v;
}

// ---------------------------------------------------------------------------
// QKV GEMM: 128x128 tile, BK=64, 4 waves (2x2), single product, chunk-major
// LDS [kc][row][8], 2 barriers/chunk. Grid 768 = 3 blocks/CU all-resident.
// 2D XCD-region swizzle (12bx x 8by per XCD).
// Fused epilogue: seg 0 -> Qh, 1 -> Kh (in-register l2norm; f16
// [b][h][t][dk]); 2 -> Vt DIRECTLY chunk-major [bh][T/8][64][8].
// ---------------------------------------------------------------------------
__global__ __launch_bounds__(256, 3) void gemm_qkv(
    const _Float16* __restrict__ Ah_g, const _Float16* __restrict__ B_g,
    _Float16* __restrict__ Qh, _Float16* __restrict__ Kh,
    _Float16* __restrict__ Vt, int K)
{
    __shared__ _Float16 Ahs[8][128][8];   // 16 KB
    __shared__ _Float16 Bhs[8][128][8];   // 16 KB

    // 2D XCD-region swizzle: grid 24bx x 32by; regions 12bx x 8by per XCD.
    const int wgid = blockIdx.x;
    const int xcd  = wgid & 7;
    const int idx  = wgid >> 3;            // 0..95
    const int by   = (xcd >> 1) * 8  + idx / 12;
    const int bx   = (xcd & 1) * 12 + idx % 12;

    const int t    = threadIdx.x;
    const int m0   = by * 128;
    const int n0g  = bx * 128;
    const int seg  = n0g >> 10;
    const int n0   = n0g & 1023;

    const int lane = t & 63;
    const int w    = t >> 6;
    const int wm   = w >> 1;
    const int wn   = w & 1;
    const int l15  = lane & 15;
    const int quad = lane >> 4;

    f32x4 acc[4][4];
#pragma unroll
    for (int i = 0; i < 4; ++i)
#pragma unroll
        for (int j = 0; j < 4; ++j) acc[i][j] = (f32x4)0.f;

    for (int k0 = 0; k0 < K; k0 += 64) {
        __syncthreads();   // previous chunk's frag reads done
#pragma unroll
        for (int i = 0; i < 2; ++i) {
            const int cc = w * 2 + i;
#pragma unroll
            for (int half = 0; half < 2; ++half) {
                g2lds16(Ah_g + (size_t)(m0 + half * 64 + lane) * K + k0 + cc * 8,
                        &Ahs[cc][half * 64][0]);
                g2lds16(B_g + (size_t)(n0g + half * 64 + lane) * K + k0 + cc * 8,
                        &Bhs[cc][half * 64][0]);
            }
        }
        __syncthreads();   // vmcnt drained

#pragma unroll
        for (int kh = 0; kh < 2; ++kh) {
            f16x8 ah[4], bh[4];
#pragma unroll
            for (int tm = 0; tm < 4; ++tm)
                ah[tm] = *(const f16x8*)&Ahs[kh * 4 + quad][wm * 64 + tm * 16 + l15][0];
#pragma unroll
            for (int tn = 0; tn < 4; ++tn)
                bh[tn] = *(const f16x8*)&Bhs[kh * 4 + quad][wn * 64 + tn * 16 + l15][0];
#pragma unroll
            for (int tm = 0; tm < 4; ++tm)
#pragma unroll
                for (int tn = 0; tn < 4; ++tn)
                    acc[tm][tn] = __builtin_amdgcn_mfma_f32_16x16x32_f16(
                        ah[tm], bh[tn], acc[tm][tn], 0, 0, 0);
        }
    }

    if (seg < 2) {
        // normalize each row's 64-wide head segment, emit f16 [b][h][t][dk]
        _Float16* __restrict__ dstb = (seg == 0) ? Qh : Kh;
        const int hh = (n0 >> 6) + wn;   // head index
#pragma unroll
        for (int tm = 0; tm < 4; ++tm) {
#pragma unroll
            for (int r = 0; r < 4; ++r) {
                float ss = 0.f;
#pragma unroll
                for (int tn = 0; tn < 4; ++tn) {
                    const float v = acc[tm][tn][r];
                    ss += v * v;
                }
                ss += __shfl_xor(ss, 1);
                ss += __shfl_xor(ss, 2);
                ss += __shfl_xor(ss, 4);
                ss += __shfl_xor(ss, 8);
                const float inv = __builtin_amdgcn_rsqf(fmaxf(ss, 1e-24f));
                const int row = m0 + wm * 64 + tm * 16 + quad * 4 + r;
                const int b   = row >> 11;
                const int tt  = row & 2047;
                _Float16* dst = dstb + ((size_t)(b * HH + hh) * TT + tt) * DK;
#pragma unroll
                for (int tn = 0; tn < 4; ++tn)
                    dst[tn * 16 + l15] = (_Float16)(acc[tm][tn][r] * inv);
            }
        }
    } else {
        // V: write DIRECTLY chunk-major Vt[bh][T/8][64][8]. Lane's acc
        // column = 4 consecutive tokens = int2 at elem offset e in {0,4}.
        const int hh = (n0 >> 6) + wn;
#pragma unroll
        for (int tm = 0; tm < 4; ++tm) {
            const int row = m0 + wm * 64 + tm * 16 + quad * 4;
            const int b   = row >> 11;
            const int tt  = row & 2047;
            const int c   = tt >> 3;       // key chunk
            const int e   = tt & 7;        // 0 or 4
            _Float16* dstc = Vt
                + ((size_t)(b * HH + hh) * (TT >> 3) + c) * (64 * 8) + e;
#pragma unroll
            for (int tn = 0; tn < 4; ++tn) {
                const int d = tn * 16 + l15;
                union { _Float16 h[4]; int2 v; } uu;
                uu.h[0] = (_Float16)acc[tm][tn][0];
                uu.h[1] = (_Float16)acc[tm][tn][1];
                uu.h[2] = (_Float16)acc[tm][tn][2];
                uu.h[3] = (_Float16)acc[tm][tn][3];
                *(int2*)(dstc + d * 8) = uu.v;
            }
        }
    }
}

// ---------------------------------------------------------------------------
// Wo GEMM: out = (Oh + Ol) @ Woh^T + bo. 128x128 tile, BK=64, hi/lo split
// A (2 products). Grid 256 = 1 block/CU -> LDS double-buffered (96 KB)
// 1-barrier ping-pong: stage(next) issues before compute(cur), so the
// next barrier's vmcnt drain gets one compute-chunk (~800cyc) of cover.
// 2D XCD-region swizzle (4bx x 8by per XCD).
// ---------------------------------------------------------------------------
__global__ __launch_bounds__(256) void gemm_wo(
    const _Float16* __restrict__ Ah_g, const _Float16* __restrict__ Al_g,
    const _Float16* __restrict__ B_g, const float* __restrict__ bias,
    float* __restrict__ C, int K)
{
    __shared__ _Float16 Ahs[2][8][128][8];   // 32 KB
    __shared__ _Float16 Als[2][8][128][8];   // 32 KB
    __shared__ _Float16 Bhs[2][8][128][8];   // 32 KB

    // 2D XCD-region swizzle: grid 8bx x 32by; regions 4bx x 8by per XCD.
    const int wgid = blockIdx.x;
    const int xcd  = wgid & 7;
    const int idx  = wgid >> 3;            // 0..31
    const int by   = (xcd >> 1) * 8 + idx / 4;
    const int bx   = (xcd & 1) * 4 + idx % 4;

    const int t    = threadIdx.x;
    const int m0   = by * 128;
    const int n0g  = bx * 128;

    const int lane = t & 63;
    const int w    = t >> 6;
    const int wm   = w >> 1;
    const int wn   = w & 1;
    const int l15  = lane & 15;
    const int quad = lane >> 4;

    f32x4 acc[4][4];
#pragma unroll
    for (int i = 0; i < 4; ++i)
#pragma unroll
        for (int j = 0; j < 4; ++j) acc[i][j] = (f32x4)0.f;

    auto STAGE = [&](int bf, int k0) {
#pragma unroll
        for (int i = 0; i < 2; ++i) {
            const int cc = w * 2 + i;
#pragma unroll
            for (int half = 0; half < 2; ++half) {
                g2lds16(Ah_g + (size_t)(m0 + half * 64 + lane) * K + k0 + cc * 8,
                        &Ahs[bf][cc][half * 64][0]);
                g2lds16(Al_g + (size_t)(m0 + half * 64 + lane) * K + k0 + cc * 8,
                        &Als[bf][cc][half * 64][0]);
                g2lds16(B_g + (size_t)(n0g + half * 64 + lane) * K + k0 + cc * 8,
                        &Bhs[bf][cc][half * 64][0]);
            }
        }
    };

    STAGE(0, 0);
    int cur = 0;
    for (int k0 = 0; k0 < K; k0 += 64) {
        __syncthreads();   // stage(cur) arrived; compute on cur^1 done
        if (k0 + 64 < K) STAGE(cur ^ 1, k0 + 64);

#pragma unroll
        for (int kh = 0; kh < 2; ++kh) {
            f16x8 ah[4], al[4], bh[4];
#pragma unroll
            for (int tm = 0; tm < 4; ++tm) {
                ah[tm] = *(const f16x8*)&Ahs[cur][kh * 4 + quad][wm * 64 + tm * 16 + l15][0];
                al[tm] = *(const f16x8*)&Als[cur][kh * 4 + quad][wm * 64 + tm * 16 + l15][0];
            }
#pragma unroll
            for (int tn = 0; tn < 4; ++tn)
                bh[tn] = *(const f16x8*)&Bhs[cur][kh * 4 + quad][wn * 64 + tn * 16 + l15][0];
#pragma unroll
            for (int tm = 0; tm < 4; ++tm)
#pragma unroll
                for (int tn = 0; tn < 4; ++tn)
                    acc[tm][tn] = __builtin_amdgcn_mfma_f32_16x16x32_f16(
                        ah[tm], bh[tn], acc[tm][tn], 0, 0, 0);
#pragma unroll
            for (int tm = 0; tm < 4; ++tm)
#pragma unroll
                for (int tn = 0; tn < 4; ++tn)
                    acc[tm][tn] = __builtin_amdgcn_mfma_f32_16x16x32_f16(
                        al[tm], bh[tn], acc[tm][tn], 0, 0, 0);
        }
        cur ^= 1;
    }

#pragma unroll
    for (int tm = 0; tm < 4; ++tm)
#pragma unroll
        for (int tn = 0; tn < 4; ++tn) {
            const int col  = n0g + wn * 64 + tn * 16 + l15;
            const float bv = bias[col];
            const int rowb = m0 + wm * 64 + tm * 16 + quad * 4;
#pragma unroll
            for (int r = 0; r < 4; ++r)
                C[(size_t)(rowb + r) * 1024 + col] = acc[tm][tn][r] + bv;
        }
}

// ---------------------------------------------------------------------------
// MFMA angular attention v13 — all-f16. Grid 1024 (1D), 256 threads.
// KT=64, LDS 36.1 KB, 4 blocks/CU, ONE barrier per tile (Ws + Vts
// double-buffered; V staged a full tile ahead; K frags prefetched in
// registers). Raw v_sqrt transform. Vt chunk-major (coalesced staging).
// (b,h)-XCD swizzle: FETCH_SIZE 69.7 -> 12.3 MB (verified R13).
// v13: s_setprio(1) around MFMA clusters (T5). Regime: 4 independent
// blocks/CU at different phases (m191-positive, not m190's lockstep) —
// scheduler can favor the MFMA-issuing wave over other blocks' VALU.
// ---------------------------------------------------------------------------
__global__ __launch_bounds__(256, 4) void attn_kernel(
    const _Float16* __restrict__ Qh_g, const _Float16* __restrict__ Kh_g,
    const _Float16* __restrict__ Vt_g,
    _Float16* __restrict__ Oh, _Float16* __restrict__ Ol)
{
    __shared__ _Float16 Vts[2][8][64][8];  // [buf][key-chunk][d][8] 16384 B
    __shared__ _Float16 Ws[2][64][72];     // [buf][q][key]          18432 B
    __shared__ float Rbuf[4][64];          //                         1024 B
    __shared__ float Rfin[64];             //                          256 B

    const int t    = threadIdx.x;
    const int lane = t & 63;
    const int w    = t >> 6;
    const int l15  = lane & 15;
    const int quad = lane >> 4;

    // (b,h)-XCD swizzle: bid = [qb:5][bhp_lo:2][xcd:3]; each XCD owns
    // bhp = xcd*4 .. xcd*4+3 entirely (bijective).
    const int bid = blockIdx.x;
    const int xcd = bid & 7;
    const int idx = bid >> 3;              // 0..127
    const int bhp = (xcd << 2) | (idx >> 5);   // 0..31
    const int qb  = idx & 31;              // q-block 0..31
    const int q0  = qb * 64;
    const int h   = bhp & 15;
    const int b   = bhp >> 4;
    const size_t bh = (size_t)(b * HH + h);

    const _Float16* kh_g = Kh_g + bh * TT * DK;
    const _Float16* vt_g = Vt_g + bh * (size_t)(TT >> 3) * (64 * 8);

    // Q fragments in registers (loaded once, L2-served)
    f16x8 qf[4][2];
#pragma unroll
    for (int qt = 0; qt < 4; ++qt)
#pragma unroll
        for (int s = 0; s < 2; ++s)
            qf[qt][s] = *(const f16x8*)(Qh_g + (bh * TT + q0 + qt * 16 + l15) * DK
                                        + s * 32 + quad * 8);

    // K fragments for tile 0 (wave's 16 keys; 16B contiguous per lane)
    f16x8 kf[2], kfn[2];
#pragma unroll
    for (int s = 0; s < 2; ++s) {
        kf[s] = *(const f16x8*)(kh_g
            + (size_t)(w * 16 + l15) * DK + s * 32 + quad * 8);
        kfn[s] = kf[s];
    }

    // stage V tile 0 into buffer 0 (coalesced chunk-major reads)
#pragma unroll
    for (int j = 0; j < 2; ++j) {
        const int kc = w * 2 + j;
        g2lds16(vt_g + (size_t)kc * (64 * 8) + lane * 8, &Vts[0][kc][0][0]);
    }

    f32x4 acc[4];    // O[16q x 64d] for q-tile w
#pragma unroll
    for (int j = 0; j < 4; ++j) acc[j] = (f32x4)0.f;
    f32x2 rs2[4];
#pragma unroll
    for (int j = 0; j < 4; ++j) rs2[j] = (f32x2)0.f;

    int p = 0;
    for (int k0 = 0; k0 < TT; k0 += KT, p ^= 1) {
        const int kn = k0 + KT;
        if (kn < TT) {
            // prefetch K fragments for tile t+1 (consumed after kf roll)
#pragma unroll
            for (int s = 0; s < 2; ++s)
                kfn[s] = *(const f16x8*)(kh_g
                    + (size_t)(kn + w * 16 + l15) * DK + s * 32 + quad * 8);
        }

        // Phase A: S^T for wave's 16 keys x 64 q, transform, write Ws[p]
#pragma unroll
        for (int qt = 0; qt < 4; ++qt) {
            f32x4 c_ = (f32x4)0.f;
            __builtin_amdgcn_s_setprio(1);
#pragma unroll
            for (int s = 0; s < 2; ++s)
                c_ = __builtin_amdgcn_mfma_f32_16x16x32_f16(
                    kf[s], qf[qt][s], c_, 0, 0, 0);
            __builtin_amdgcn_s_setprio(0);
            f32x2 p01, p23;
            p01.x = c_[0]; p01.y = c_[1];
            p23.x = c_[2]; p23.y = c_[3];
            f32x2 w01 = w8pair(p01, rs2[qt]);
            f32x2 w23 = w8pair(p23, rs2[qt]);
            int2 pk;
            pk.x = packh2(w01);
            pk.y = packh2(w23);
            *(int2*)&Ws[p][qt * 16 + l15][w * 16 + quad * 4] = pk;
        }
        __syncthreads();   // BAR(t): Ws[p] ready; V[t] arrived (staged t-1);
                           // B(t-1)'s Ws[p^1]/Vts[p^1] reads drained

        if (kn < TT) {
            // stage V[t+1] into the other buffer (consumed after BAR(t+1))
#pragma unroll
            for (int j = 0; j < 2; ++j) {
                const int kc = w * 2 + j;
                g2lds16(vt_g + ((size_t)(kn >> 3) + kc) * (64 * 8) + lane * 8,
                        &Vts[p ^ 1][kc][0][0]);
            }
        }

        // Phase B: PV for q-tile w over the tile's 64 keys from Vts[p]
        __builtin_amdgcn_s_setprio(1);
#pragma unroll
        for (int kstep = 0; kstep < 2; ++kstep) {
            f16x8 av = *(const f16x8*)&Ws[p][16 * w + l15][kstep * 32 + quad * 8];
#pragma unroll
            for (int nd = 0; nd < 4; ++nd) {
                f16x8 bv = *(const f16x8*)&Vts[p][kstep * 4 + quad][nd * 16 + l15][0];
                acc[nd] = __builtin_amdgcn_mfma_f32_16x16x32_f16(
                    av, bv, acc[nd], 0, 0, 0);
            }
        }
        __builtin_amdgcn_s_setprio(0);

        // roll K prefetch
#pragma unroll
        for (int s = 0; s < 2; ++s)
            kf[s] = kfn[s];
    }

    // rowsum: rs2[qt] covers q = qt*16+l15 over this lane's key slots
#pragma unroll
    for (int qt = 0; qt < 4; ++qt) {
        float pr = rs2[qt].x + rs2[qt].y;
        pr += __shfl_xor(pr, 16);
        pr += __shfl_xor(pr, 32);
        if (quad == 0) Rbuf[w][qt * 16 + l15] = pr;
    }
    __syncthreads();
    if (t < 64) {
        float s = Rbuf[0][t] + Rbuf[1][t] + Rbuf[2][t] + Rbuf[3][t];
        Rfin[t] = 1.f / (s + 1e-6f);
    }
    __syncthreads();

    // store: O split hi/lo f16 (feeds the NPROD=2 Wo GEMM)
#pragma unroll
    for (int r = 0; r < 4; ++r) {
        const int q = 16 * w + quad * 4 + r;
        const float inv = Rfin[q];
        const size_t base = (size_t)(b * TT + q0 + q) * DD + h * DK + l15;
#pragma unroll
        for (int nd = 0; nd < 4; ++nd) {
            float v = acc[nd][r] * inv;
            _Float16 hv = (_Float16)v;
            Oh[base + nd * 16] = hv;
            Ol[base + nd * 16] = (_Float16)(v - (float)hv);
        }
    }
}

// ---------------------------------------------------------------------------
extern "C" void kernel_launch(void* const* d_in, const int* in_sizes, int n_in,
                              void* d_out, int out_size, void* d_ws, size_t ws_size,
                              hipStream_t stream)
{
    const float* x  = (const float*)d_in[0];
    const float* Wq = (const float*)d_in[1];
    const float* Wk = (const float*)d_in[2];
    const float* Wv = (const float*)d_in[3];
    const float* Wo = (const float*)d_in[4];
    const float* bo = (const float*)d_in[5];
    float* out = (float*)d_out;

    const size_t MB = 1024 * 1024;
    char* ws = (char*)d_ws;
    // [0,8):   xh f16      -> Oh f16 (xh dead after QKV GEMM)
    // [8,14):  W3h f16 = [Wq;Wk;Wv] rows (3072x1024, 6 MB)
    // [14,16): Woh f16 (persists)
    // [16,24): Qh f16 (normalized, [b][h][t][dk])
    // [24,32): Kh f16 (normalized)
    // [32,40): Ol f16
    // [40,48): Vt f16 chunk-major [bh][T/8][64][8] (written by QKV GEMM)
    _Float16* xh  = (_Float16*)(ws);
    _Float16* W3h = (_Float16*)(ws + 8 * MB);
    _Float16* Woh = (_Float16*)(ws + 14 * MB);
    _Float16* Qh  = (_Float16*)(ws + 16 * MB);
    _Float16* Kh  = (_Float16*)(ws + 24 * MB);
    _Float16* Ol  = (_Float16*)(ws + 32 * MB);
    _Float16* Vt  = (_Float16*)(ws + 40 * MB);
    _Float16* Oh  = (_Float16*)(ws);            // xh dead after QKV GEMM

    dim3 gB(256);

    // 1) convert x + weights to f16 (one launch)
    cvtall_kernel<<<4096, gB, 0, stream>>>(x, Wq, Wk, Wv, Wo, xh, W3h, Woh);

    // 2) fused QKV projection (128x128, 768 blocks = 3/CU all-resident):
    //    l2norm epilogue -> Qh/Kh; V -> Vt directly chunk-major.
    gemm_qkv<<<768, gB, 0, stream>>>(xh, W3h, Qh, Kh, Vt, DD);

    // 3) fused angular attention -> O split hi/lo f16 ((b,h)-XCD swizzle,
    //    setprio around MFMA)
    attn_kernel<<<1024, gB, 0, stream>>>(Qh, Kh, Vt, Oh, Ol);

    // 4) output projection: (Oh + Ol) @ Woh^T + bo (dbuf ping-pong;
    //    2D XCD-region swizzle)
    gemm_wo<<<256, gB, 0, stream>>>(Oh, Ol, Woh, bo, out, DD);
}

// Round 15
// 254.024 us; speedup vs baseline: 1.0202x; 1.0202x over previous
//
#include <hip/hip_runtime.h>
#include <hip/hip_bf16.h>
#include <hip/hip_fp16.h>
#include <math.h>

// Problem constants
#define BB 2
#define TT 2048
#define DD 1024
#define HH 16
#define DK 64
#define KT 64             // keys per attention tile

typedef _Float16 f16x8 __attribute__((ext_vector_type(8)));
typedef __fp16 fp16x2 __attribute__((ext_vector_type(2)));
typedef __attribute__((ext_vector_type(4))) float f32x4;
typedef __attribute__((ext_vector_type(2))) float f32x2;

// async 16B global->LDS (lane i writes ldsbase + i*16)
static __device__ __forceinline__ void g2lds16(const void* g, void* l) {
    __builtin_amdgcn_global_load_lds(
        (const __attribute__((address_space(1))) unsigned int*)g,
        (__attribute__((address_space(3))) unsigned int*)l, 16, 0, 0);
}

// w = (1 - acos(clip(s,±0.999))/pi)^8 for a pair; rs accumulates pair sums.
// acos/pi via A&S 4.4.45 deg-3 (|err|<=5e-5 rad); reference's max(.,1e-6)
// is dead (clamp => t >= 0.0142). float2 ops lower to v_pk_* on gfx950.
// __builtin_amdgcn_sqrtf = raw v_sqrt_f32 (~1ulp, om in [1e-3,2] safe) —
// avoids the IEEE fixup sequence libm sqrtf emits (R7: -34% attn time).
static __device__ __forceinline__ f32x2 w8pair(f32x2 s, f32x2& rs) {
    f32x2 ax;
    ax.x = fminf(fabsf(s.x), 0.999f);
    ax.y = fminf(fabsf(s.y), 0.999f);
    f32x2 p = ax * -0.0059617f + 0.0236380f;
    p = p * ax + (-0.0675180f);
    p = p * ax + 0.49997851f;
    f32x2 om = 1.0f - ax;
    f32x2 u;
    u.x = __builtin_amdgcn_sqrtf(om.x);
    u.y = __builtin_amdgcn_sqrtf(om.y);
    f32x2 uq = u * p;
    f32x2 e = 0.5f - uq;
    f32x2 t;
    t.x = 0.5f + copysignf(e.x, s.x);
    t.y = 0.5f + copysignf(e.y, s.y);
    f32x2 t2 = t * t;
    f32x2 t4 = t2 * t2;
    f32x2 t8 = t4 * t4;
    rs += t8;
    return t8;
}
// one-instruction f16 pair pack (RTZ; |err|<=2^-11 rel, fine for W)
static __device__ __forceinline__ int packh2(f32x2 v) {
    union { fp16x2 h; int i; } u;
    u.h = __builtin_amdgcn_cvt_pkrtz(v.x, v.y);
    return u.i;
}

// ---------------------------------------------------------------------------
// One-launch fp32 -> f16 convert for x + all 4 weight matrices.
// bid < 2048: x -> xh. Wq/Wk/Wv -> W3h rows (contiguous). Wo -> Woh.
// ---------------------------------------------------------------------------
__global__ __launch_bounds__(256) void cvtall_kernel(
    const float* __restrict__ x,  const float* __restrict__ Wq,
    const float* __restrict__ Wk, const float* __restrict__ Wv,
    const float* __restrict__ Wo,
    _Float16* __restrict__ xh, _Float16* __restrict__ W3h,
    _Float16* __restrict__ Woh)
{
    const int bid = blockIdx.x;
    const float* s; _Float16* d; int blk;
    if (bid < 2048) { s = x; d = xh; blk = bid; }
    else {
        const int idx = bid - 2048;
        const int w   = idx >> 9;          // 0..3
        blk = idx & 511;
        s = (w == 0) ? Wq : (w == 1) ? Wk : (w == 2) ? Wv : Wo;
        d = (w == 3) ? Woh : W3h + (size_t)w * (DD * DD);
    }
    const int i = (blk * 256 + threadIdx.x) * 8;
    float4 a = *(const float4*)(s + i);
    float4 b = *(const float4*)(s + i + 4);
    union { _Float16 h[8]; int4 v; } u;
    u.h[0] = (_Float16)a.x; u.h[1] = (_Float16)a.y;
    u.h[2] = (_Float16)a.z; u.h[3] = (_Float16)a.w;
    u.h[4] = (_Float16)b.x; u.h[5] = (_Float16)b.y;
    u.h[6] = (_Float16)b.z; u.h[7] = (_Float16)b.w;
    *(int4*)(d + i) = u.v;
}

// ---------------------------------------------------------------------------
// QKV GEMM (R15): 128x128 tile, BK=64, *** 512 threads = 8 waves (4m x 2n,
// each wave 32 rows x 64 cols) ***. Same grid (768), same LDS (32 KB), same
// traffic as the 4-wave version — but 24 waves/CU (6/SIMD) instead of 12,
// so ds_read->MFMA chains and barrier drains overlap across 2x more waves.
// launch_bounds(512,6) pins VGPR <= ~84 for 3 blocks/CU residency.
// Each wave spans a FULL 64-wide head -> norm epilogue stays wave-local.
// 2D XCD-region swizzle (12bx x 8by per XCD).
// Fused epilogue: seg 0 -> Qh, 1 -> Kh (in-register l2norm; f16
// [b][h][t][dk]); 2 -> Vt DIRECTLY chunk-major [bh][T/8][64][8].
// ---------------------------------------------------------------------------
__global__ __launch_bounds__(512, 6) void gemm_qkv(
    const _Float16* __restrict__ Ah_g, const _Float16* __restrict__ B_g,
    _Float16* __restrict__ Qh, _Float16* __restrict__ Kh,
    _Float16* __restrict__ Vt, int K)
{
    __shared__ _Float16 Ahs[8][128][8];   // 16 KB
    __shared__ _Float16 Bhs[8][128][8];   // 16 KB

    // 2D XCD-region swizzle: grid 24bx x 32by; regions 12bx x 8by per XCD.
    const int wgid = blockIdx.x;
    const int xcd  = wgid & 7;
    const int idx  = wgid >> 3;            // 0..95
    const int by   = (xcd >> 1) * 8  + idx / 12;
    const int bx   = (xcd & 1) * 12 + idx % 12;

    const int t    = threadIdx.x;
    const int m0   = by * 128;
    const int n0g  = bx * 128;
    const int seg  = n0g >> 10;
    const int n0   = n0g & 1023;

    const int lane = t & 63;
    const int w    = t >> 6;        // 0..7
    const int wm   = w >> 1;        // 0..3 (32-row slab)
    const int wn   = w & 1;         // 0..1 (64-col slab = one head)
    const int l15  = lane & 15;
    const int quad = lane >> 4;

    f32x4 acc[2][4];
#pragma unroll
    for (int i = 0; i < 2; ++i)
#pragma unroll
        for (int j = 0; j < 4; ++j) acc[i][j] = (f32x4)0.f;

    for (int k0 = 0; k0 < K; k0 += 64) {
        __syncthreads();   // previous chunk's frag reads done
        // staging: wave w handles chunk cc = w (8 chunks, 8 waves)
        {
            const int cc = w;
#pragma unroll
            for (int half = 0; half < 2; ++half) {
                g2lds16(Ah_g + (size_t)(m0 + half * 64 + lane) * K + k0 + cc * 8,
                        &Ahs[cc][half * 64][0]);
                g2lds16(B_g + (size_t)(n0g + half * 64 + lane) * K + k0 + cc * 8,
                        &Bhs[cc][half * 64][0]);
            }
        }
        __syncthreads();   // vmcnt drained

#pragma unroll
        for (int kh = 0; kh < 2; ++kh) {
            f16x8 ah[2], bh[4];
#pragma unroll
            for (int tm = 0; tm < 2; ++tm)
                ah[tm] = *(const f16x8*)&Ahs[kh * 4 + quad][wm * 32 + tm * 16 + l15][0];
#pragma unroll
            for (int tn = 0; tn < 4; ++tn)
                bh[tn] = *(const f16x8*)&Bhs[kh * 4 + quad][wn * 64 + tn * 16 + l15][0];
#pragma unroll
            for (int tm = 0; tm < 2; ++tm)
#pragma unroll
                for (int tn = 0; tn < 4; ++tn)
                    acc[tm][tn] = __builtin_amdgcn_mfma_f32_16x16x32_f16(
                        ah[tm], bh[tn], acc[tm][tn], 0, 0, 0);
        }
    }

    if (seg < 2) {
        // normalize each row's 64-wide head segment, emit f16 [b][h][t][dk]
        _Float16* __restrict__ dstb = (seg == 0) ? Qh : Kh;
        const int hh = (n0 >> 6) + wn;   // head index
#pragma unroll
        for (int tm = 0; tm < 2; ++tm) {
#pragma unroll
            for (int r = 0; r < 4; ++r) {
                float ss = 0.f;
#pragma unroll
                for (int tn = 0; tn < 4; ++tn) {
                    const float v = acc[tm][tn][r];
                    ss += v * v;
                }
                ss += __shfl_xor(ss, 1);
                ss += __shfl_xor(ss, 2);
                ss += __shfl_xor(ss, 4);
                ss += __shfl_xor(ss, 8);
                const float inv = __builtin_amdgcn_rsqf(fmaxf(ss, 1e-24f));
                const int row = m0 + wm * 32 + tm * 16 + quad * 4 + r;
                const int b   = row >> 11;
                const int tt  = row & 2047;
                _Float16* dst = dstb + ((size_t)(b * HH + hh) * TT + tt) * DK;
#pragma unroll
                for (int tn = 0; tn < 4; ++tn)
                    dst[tn * 16 + l15] = (_Float16)(acc[tm][tn][r] * inv);
            }
        }
    } else {
        // V: write DIRECTLY chunk-major Vt[bh][T/8][64][8]. Lane's acc
        // column = 4 consecutive tokens = int2 at elem offset e in {0,4}.
        const int hh = (n0 >> 6) + wn;
#pragma unroll
        for (int tm = 0; tm < 2; ++tm) {
            const int row = m0 + wm * 32 + tm * 16 + quad * 4;
            const int b   = row >> 11;
            const int tt  = row & 2047;
            const int c   = tt >> 3;       // key chunk
            const int e   = tt & 7;        // 0 or 4
            _Float16* dstc = Vt
                + ((size_t)(b * HH + hh) * (TT >> 3) + c) * (64 * 8) + e;
#pragma unroll
            for (int tn = 0; tn < 4; ++tn) {
                const int d = tn * 16 + l15;
                union { _Float16 h[4]; int2 v; } uu;
                uu.h[0] = (_Float16)acc[tm][tn][0];
                uu.h[1] = (_Float16)acc[tm][tn][1];
                uu.h[2] = (_Float16)acc[tm][tn][2];
                uu.h[3] = (_Float16)acc[tm][tn][3];
                *(int2*)(dstc + d * 8) = uu.v;
            }
        }
    }
}

// ---------------------------------------------------------------------------
// Wo GEMM (R15): out = (Oh + Ol) @ Woh^T + bo. 128x128 tile, BK=64, hi/lo
// split A (2 products). *** 512 threads = 8 waves (4m x 2n) *** -> 8
// waves/CU (2/SIMD) instead of 4 (1/SIMD): a lone wave/SIMD could hide NO
// latency. Grid 256 = 1 block/CU; LDS double-buffered (96 KB) 1-barrier
// ping-pong. 2D XCD-region swizzle (4bx x 8by per XCD).
// ---------------------------------------------------------------------------
__global__ __launch_bounds__(512, 2) void gemm_wo(
    const _Float16* __restrict__ Ah_g, const _Float16* __restrict__ Al_g,
    const _Float16* __restrict__ B_g, const float* __restrict__ bias,
    float* __restrict__ C, int K)
{
    __shared__ _Float16 Ahs[2][8][128][8];   // 32 KB
    __shared__ _Float16 Als[2][8][128][8];   // 32 KB
    __shared__ _Float16 Bhs[2][8][128][8];   // 32 KB

    // 2D XCD-region swizzle: grid 8bx x 32by; regions 4bx x 8by per XCD.
    const int wgid = blockIdx.x;
    const int xcd  = wgid & 7;
    const int idx  = wgid >> 3;            // 0..31
    const int by   = (xcd >> 1) * 8 + idx / 4;
    const int bx   = (xcd & 1) * 4 + idx % 4;

    const int t    = threadIdx.x;
    const int m0   = by * 128;
    const int n0g  = bx * 128;

    const int lane = t & 63;
    const int w    = t >> 6;        // 0..7
    const int wm   = w >> 1;        // 0..3
    const int wn   = w & 1;         // 0..1
    const int l15  = lane & 15;
    const int quad = lane >> 4;

    f32x4 acc[2][4];
#pragma unroll
    for (int i = 0; i < 2; ++i)
#pragma unroll
        for (int j = 0; j < 4; ++j) acc[i][j] = (f32x4)0.f;

    auto STAGE = [&](int bf, int k0) {
        const int cc = w;            // wave w stages chunk w
#pragma unroll
        for (int half = 0; half < 2; ++half) {
            g2lds16(Ah_g + (size_t)(m0 + half * 64 + lane) * K + k0 + cc * 8,
                    &Ahs[bf][cc][half * 64][0]);
            g2lds16(Al_g + (size_t)(m0 + half * 64 + lane) * K + k0 + cc * 8,
                    &Als[bf][cc][half * 64][0]);
            g2lds16(B_g + (size_t)(n0g + half * 64 + lane) * K + k0 + cc * 8,
                    &Bhs[bf][cc][half * 64][0]);
        }
    };

    STAGE(0, 0);
    int cur = 0;
    for (int k0 = 0; k0 < K; k0 += 64) {
        __syncthreads();   // stage(cur) arrived; compute on cur^1 done
        if (k0 + 64 < K) STAGE(cur ^ 1, k0 + 64);

#pragma unroll
        for (int kh = 0; kh < 2; ++kh) {
            f16x8 ah[2], al[2], bh[4];
#pragma unroll
            for (int tm = 0; tm < 2; ++tm) {
                ah[tm] = *(const f16x8*)&Ahs[cur][kh * 4 + quad][wm * 32 + tm * 16 + l15][0];
                al[tm] = *(const f16x8*)&Als[cur][kh * 4 + quad][wm * 32 + tm * 16 + l15][0];
            }
#pragma unroll
            for (int tn = 0; tn < 4; ++tn)
                bh[tn] = *(const f16x8*)&Bhs[cur][kh * 4 + quad][wn * 64 + tn * 16 + l15][0];
#pragma unroll
            for (int tm = 0; tm < 2; ++tm)
#pragma unroll
                for (int tn = 0; tn < 4; ++tn)
                    acc[tm][tn] = __builtin_amdgcn_mfma_f32_16x16x32_f16(
                        ah[tm], bh[tn], acc[tm][tn], 0, 0, 0);
#pragma unroll
            for (int tm = 0; tm < 2; ++tm)
#pragma unroll
                for (int tn = 0; tn < 4; ++tn)
                    acc[tm][tn] = __builtin_amdgcn_mfma_f32_16x16x32_f16(
                        al[tm], bh[tn], acc[tm][tn], 0, 0, 0);
        }
        cur ^= 1;
    }

#pragma unroll
    for (int tm = 0; tm < 2; ++tm)
#pragma unroll
        for (int tn = 0; tn < 4; ++tn) {
            const int col  = n0g + wn * 64 + tn * 16 + l15;
            const float bv = bias[col];
            const int rowb = m0 + wm * 32 + tm * 16 + quad * 4;
#pragma unroll
            for (int r = 0; r < 4; ++r)
                C[(size_t)(rowb + r) * 1024 + col] = acc[tm][tn][r] + bv;
        }
}

// ---------------------------------------------------------------------------
// MFMA angular attention v12 — all-f16. Grid 1024 (1D), 256 threads.
// KT=64, LDS 36.1 KB, 4 blocks/CU, ONE barrier per tile (Ws + Vts
// double-buffered; V staged a full tile ahead; K frags prefetched in
// registers). Raw v_sqrt transform. Vt chunk-major (coalesced staging).
// (b,h)-XCD swizzle: FETCH_SIZE 69.7 -> 12.3 MB (verified R13).
// (setprio reverted: R14 A/B showed null/-1% for 4-wave-block attn.)
// ---------------------------------------------------------------------------
__global__ __launch_bounds__(256, 4) void attn_kernel(
    const _Float16* __restrict__ Qh_g, const _Float16* __restrict__ Kh_g,
    const _Float16* __restrict__ Vt_g,
    _Float16* __restrict__ Oh, _Float16* __restrict__ Ol)
{
    __shared__ _Float16 Vts[2][8][64][8];  // [buf][key-chunk][d][8] 16384 B
    __shared__ _Float16 Ws[2][64][72];     // [buf][q][key]          18432 B
    __shared__ float Rbuf[4][64];          //                         1024 B
    __shared__ float Rfin[64];             //                          256 B

    const int t    = threadIdx.x;
    const int lane = t & 63;
    const int w    = t >> 6;
    const int l15  = lane & 15;
    const int quad = lane >> 4;

    // (b,h)-XCD swizzle: bid = [qb:5][bhp_lo:2][xcd:3]; each XCD owns
    // bhp = xcd*4 .. xcd*4+3 entirely (bijective).
    const int bid = blockIdx.x;
    const int xcd = bid & 7;
    const int idx = bid >> 3;              // 0..127
    const int bhp = (xcd << 2) | (idx >> 5);   // 0..31
    const int qb  = idx & 31;              // q-block 0..31
    const int q0  = qb * 64;
    const int h   = bhp & 15;
    const int b   = bhp >> 4;
    const size_t bh = (size_t)(b * HH + h);

    const _Float16* kh_g = Kh_g + bh * TT * DK;
    const _Float16* vt_g = Vt_g + bh * (size_t)(TT >> 3) * (64 * 8);

    // Q fragments in registers (loaded once, L2-served)
    f16x8 qf[4][2];
#pragma unroll
    for (int qt = 0; qt < 4; ++qt)
#pragma unroll
        for (int s = 0; s < 2; ++s)
            qf[qt][s] = *(const f16x8*)(Qh_g + (bh * TT + q0 + qt * 16 + l15) * DK
                                        + s * 32 + quad * 8);

    // K fragments for tile 0 (wave's 16 keys; 16B contiguous per lane)
    f16x8 kf[2], kfn[2];
#pragma unroll
    for (int s = 0; s < 2; ++s) {
        kf[s] = *(const f16x8*)(kh_g
            + (size_t)(w * 16 + l15) * DK + s * 32 + quad * 8);
        kfn[s] = kf[s];
    }

    // stage V tile 0 into buffer 0 (coalesced chunk-major reads)
#pragma unroll
    for (int j = 0; j < 2; ++j) {
        const int kc = w * 2 + j;
        g2lds16(vt_g + (size_t)kc * (64 * 8) + lane * 8, &Vts[0][kc][0][0]);
    }

    f32x4 acc[4];    // O[16q x 64d] for q-tile w
#pragma unroll
    for (int j = 0; j < 4; ++j) acc[j] = (f32x4)0.f;
    f32x2 rs2[4];
#pragma unroll
    for (int j = 0; j < 4; ++j) rs2[j] = (f32x2)0.f;

    int p = 0;
    for (int k0 = 0; k0 < TT; k0 += KT, p ^= 1) {
        const int kn = k0 + KT;
        if (kn < TT) {
            // prefetch K fragments for tile t+1 (consumed after kf roll)
#pragma unroll
            for (int s = 0; s < 2; ++s)
                kfn[s] = *(const f16x8*)(kh_g
                    + (size_t)(kn + w * 16 + l15) * DK + s * 32 + quad * 8);
        }

        // Phase A: S^T for wave's 16 keys x 64 q, transform, write Ws[p]
#pragma unroll
        for (int qt = 0; qt < 4; ++qt) {
            f32x4 c_ = (f32x4)0.f;
#pragma unroll
            for (int s = 0; s < 2; ++s)
                c_ = __builtin_amdgcn_mfma_f32_16x16x32_f16(
                    kf[s], qf[qt][s], c_, 0, 0, 0);
            f32x2 p01, p23;
            p01.x = c_[0]; p01.y = c_[1];
            p23.x = c_[2]; p23.y = c_[3];
            f32x2 w01 = w8pair(p01, rs2[qt]);
            f32x2 w23 = w8pair(p23, rs2[qt]);
            int2 pk;
            pk.x = packh2(w01);
            pk.y = packh2(w23);
            *(int2*)&Ws[p][qt * 16 + l15][w * 16 + quad * 4] = pk;
        }
        __syncthreads();   // BAR(t): Ws[p] ready; V[t] arrived (staged t-1);
                           // B(t-1)'s Ws[p^1]/Vts[p^1] reads drained

        if (kn < TT) {
            // stage V[t+1] into the other buffer (consumed after BAR(t+1))
#pragma unroll
            for (int j = 0; j < 2; ++j) {
                const int kc = w * 2 + j;
                g2lds16(vt_g + ((size_t)(kn >> 3) + kc) * (64 * 8) + lane * 8,
                        &Vts[p ^ 1][kc][0][0]);
            }
        }

        // Phase B: PV for q-tile w over the tile's 64 keys from Vts[p]
#pragma unroll
        for (int kstep = 0; kstep < 2; ++kstep) {
            f16x8 av = *(const f16x8*)&Ws[p][16 * w + l15][kstep * 32 + quad * 8];
#pragma unroll
            for (int nd = 0; nd < 4; ++nd) {
                f16x8 bv = *(const f16x8*)&Vts[p][kstep * 4 + quad][nd * 16 + l15][0];
                acc[nd] = __builtin_amdgcn_mfma_f32_16x16x32_f16(
                    av, bv, acc[nd], 0, 0, 0);
            }
        }

        // roll K prefetch
#pragma unroll
        for (int s = 0; s < 2; ++s)
            kf[s] = kfn[s];
    }

    // rowsum: rs2[qt] covers q = qt*16+l15 over this lane's key slots
#pragma unroll
    for (int qt = 0; qt < 4; ++qt) {
        float pr = rs2[qt].x + rs2[qt].y;
        pr += __shfl_xor(pr, 16);
        pr += __shfl_xor(pr, 32);
        if (quad == 0) Rbuf[w][qt * 16 + l15] = pr;
    }
    __syncthreads();
    if (t < 64) {
        float s = Rbuf[0][t] + Rbuf[1][t] + Rbuf[2][t] + Rbuf[3][t];
        Rfin[t] = 1.f / (s + 1e-6f);
    }
    __syncthreads();

    // store: O split hi/lo f16 (feeds the NPROD=2 Wo GEMM)
#pragma unroll
    for (int r = 0; r < 4; ++r) {
        const int q = 16 * w + quad * 4 + r;
        const float inv = Rfin[q];
        const size_t base = (size_t)(b * TT + q0 + q) * DD + h * DK + l15;
#pragma unroll
        for (int nd = 0; nd < 4; ++nd) {
            float v = acc[nd][r] * inv;
            _Float16 hv = (_Float16)v;
            Oh[base + nd * 16] = hv;
            Ol[base + nd * 16] = (_Float16)(v - (float)hv);
        }
    }
}

// ---------------------------------------------------------------------------
extern "C" void kernel_launch(void* const* d_in, const int* in_sizes, int n_in,
                              void* d_out, int out_size, void* d_ws, size_t ws_size,
                              hipStream_t stream)
{
    const float* x  = (const float*)d_in[0];
    const float* Wq = (const float*)d_in[1];
    const float* Wk = (const float*)d_in[2];
    const float* Wv = (const float*)d_in[3];
    const float* Wo = (const float*)d_in[4];
    const float* bo = (const float*)d_in[5];
    float* out = (float*)d_out;

    const size_t MB = 1024 * 1024;
    char* ws = (char*)d_ws;
    // [0,8):   xh f16      -> Oh f16 (xh dead after QKV GEMM)
    // [8,14):  W3h f16 = [Wq;Wk;Wv] rows (3072x1024, 6 MB)
    // [14,16): Woh f16 (persists)
    // [16,24): Qh f16 (normalized, [b][h][t][dk])
    // [24,32): Kh f16 (normalized)
    // [32,40): Ol f16
    // [40,48): Vt f16 chunk-major [bh][T/8][64][8] (written by QKV GEMM)
    _Float16* xh  = (_Float16*)(ws);
    _Float16* W3h = (_Float16*)(ws + 8 * MB);
    _Float16* Woh = (_Float16*)(ws + 14 * MB);
    _Float16* Qh  = (_Float16*)(ws + 16 * MB);
    _Float16* Kh  = (_Float16*)(ws + 24 * MB);
    _Float16* Ol  = (_Float16*)(ws + 32 * MB);
    _Float16* Vt  = (_Float16*)(ws + 40 * MB);
    _Float16* Oh  = (_Float16*)(ws);            // xh dead after QKV GEMM

    // 1) convert x + weights to f16 (one launch)
    cvtall_kernel<<<4096, 256, 0, stream>>>(x, Wq, Wk, Wv, Wo, xh, W3h, Woh);

    // 2) fused QKV projection (128x128, 768 blocks x 512 threads = 24
    //    waves/CU): l2norm epilogue -> Qh/Kh; V -> Vt chunk-major.
    gemm_qkv<<<768, 512, 0, stream>>>(xh, W3h, Qh, Kh, Vt, DD);

    // 3) fused angular attention -> O split hi/lo f16 ((b,h)-XCD swizzle)
    attn_kernel<<<1024, 256, 0, stream>>>(Qh, Kh, Vt, Oh, Ol);

    // 4) output projection: (Oh + Ol) @ Woh^T + bo (512 threads = 8
    //    waves/CU; dbuf ping-pong; 2D XCD-region swizzle)
    gemm_wo<<<256, 512, 0, stream>>>(Oh, Ol, Woh, bo, out, DD);
}